// Round 12
// baseline (204.431 us; speedup 1.0000x reference)
//
#include <hip/hip_runtime.h>
#include <hip/hip_bf16.h>
#include <cstdint>
#include <cstddef>

#define IC 512     // in_caps
#define IDM 768    // in_dim
#define KC 16      // num_caps
#define NB 128     // batch
#define NOUT 1024  // KC*DC

typedef __attribute__((ext_vector_type(8))) short short8v;
typedef __attribute__((ext_vector_type(4))) float f32x4;

#define MFMA __builtin_amdgcn_mfma_f32_16x16x32_bf16

static __device__ __forceinline__ unsigned fbits(float x) {
  union { float f; unsigned u; } z; z.f = x; return z.u;
}
static __device__ __forceinline__ float bf_f(ushort u) {
  union { float f; unsigned u32; } z; z.u32 = ((unsigned)u) << 16; return z.f;
}
static __device__ __forceinline__ ushort bf_rne(float x) {
  __hip_bfloat16 h = __float2bfloat16(x);
  return *reinterpret_cast<ushort*>(&h);
}
// truncation hi/lo split (GEMM input path only)
static __device__ __forceinline__ void split2(float x, ushort& h, ushort& l) {
  h = (ushort)(fbits(x) >> 16);
  const float r = x - bf_f(h);
  l = (ushort)(fbits(r) >> 16);
}
static __device__ __forceinline__ void split8(const float* p, short8v& h, short8v& l) {
  const float4 x0 = *(const float4*)p;
  const float4 x1 = *(const float4*)(p + 4);
  const float xs[8] = {x0.x, x0.y, x0.z, x0.w, x1.x, x1.y, x1.z, x1.w};
  #pragma unroll
  for (int j = 0; j < 8; ++j) {
    ushort hh, ll; split2(xs[j], hh, ll);
    h[j] = (short)hh; l[j] = (short)ll;
  }
}
static __device__ __forceinline__ float tanh_fast(float x) {
  const float e2 = __expf(2.0f * x);
  return 1.0f - 2.0f / (e2 + 1.0f);
}

struct KArgs {
  const float *m, *q, *Ww, *Wb;
  ushort *Hb, *HTb;          // hat_m bf16 [i][n] and [n][i]
  ushort *Yb[3];             // y per round, bf16 [b][1024]
  ushort *Vb[2];             // vsum per round, bf16 [b][1024]
  float *summT, *invxT;      // H row stats (of bf16 H): [k][i]
  float *syT[3], *invyT[3];  // y row stats per round: [k][b]
  float *outp;
};

// ===================== K1: GEMM (hi/lo f32-accurate) + bf16 epilogue ============
// Verbatim R9/R11-verified kernel.
__global__ __launch_bounds__(256) void k_gemm(KArgs A)
{
  __shared__ float sred[2][2][32];
  const int t = threadIdx.x;
  const int bid = blockIdx.x;
  const int region = bid & 7, idx = bid >> 3;
  const int rt = (region & 1) * 10 + (idx % 10);
  const int nt = (region >> 1) * 4 + (idx / 10);
  const int w = t >> 6, L = t & 63, c = L & 15, g = L >> 4;
  const int wr = w >> 1, wc = w & 1;
  const int r0 = rt * 32, n0 = nt * 64;
  const int arow = r0 + wr * 16 + c;
  const int bcol = n0 + wc * 32 + c;
  const float* asrc = (arow < IC) ? (A.m + (size_t)arow * IDM)
                                  : (A.q + (size_t)(arow - IC) * IDM);
  const float* b0src = A.Ww + (size_t)bcol * IDM;
  const float* b1src = A.Ww + (size_t)(bcol + 16) * IDM;

  f32x4 acc0 = {}, acc1 = {};
  #pragma unroll 2
  for (int kb = 0; kb < IDM; kb += 32) {
    short8v ah, al, bh0, bl0, bh1, bl1;
    split8(asrc + kb + g * 8, ah, al);
    split8(b0src + kb + g * 8, bh0, bl0);
    split8(b1src + kb + g * 8, bh1, bl1);
    acc0 = MFMA(ah, bh0, acc0, 0, 0, 0);
    acc0 = MFMA(ah, bl0, acc0, 0, 0, 0);
    acc0 = MFMA(al, bh0, acc0, 0, 0, 0);
    acc1 = MFMA(ah, bh1, acc1, 0, 0, 0);
    acc1 = MFMA(ah, bl1, acc1, 0, 0, 0);
    acc1 = MFMA(al, bh1, acc1, 0, 0, 0);
  }

  const float bias0 = A.Wb[bcol];
  const float bias1 = A.Wb[bcol + 16];
  ushort h0[4], h1[4];
  float r0s[4], r1s[4];
  #pragma unroll
  for (int j = 0; j < 4; ++j) {
    h0[j] = bf_rne(acc0[j] + bias0); r0s[j] = bf_f(h0[j]);
    h1[j] = bf_rne(acc1[j] + bias1); r1s[j] = bf_f(h1[j]);
  }

  #pragma unroll
  for (int j = 0; j < 4; ++j) {
    float s = r0s[j] + r1s[j];
    float q2 = r0s[j] * r0s[j] + r1s[j] * r1s[j];
    #pragma unroll
    for (int off = 1; off < 16; off <<= 1) {
      s += __shfl_xor(s, off);
      q2 += __shfl_xor(q2, off);
    }
    if (c == 0) {
      sred[wc][0][wr * 16 + 4 * g + j] = s;
      sred[wc][1][wr * 16 + 4 * g + j] = q2;
    }
  }

  const int rowb = r0 + wr * 16 + 4 * g;
  if (rowb < IC) {
    #pragma unroll
    for (int j = 0; j < 4; ++j) {
      const size_t r = (size_t)(rowb + j) * NOUT;
      A.Hb[r + bcol] = h0[j];
      A.Hb[r + bcol + 16] = h1[j];
    }
    *(ushort4*)&A.HTb[(size_t)bcol * 512 + rowb] = make_ushort4(h0[0], h0[1], h0[2], h0[3]);
    *(ushort4*)&A.HTb[(size_t)(bcol + 16) * 512 + rowb] = make_ushort4(h1[0], h1[1], h1[2], h1[3]);
  } else {
    #pragma unroll
    for (int j = 0; j < 4; ++j) {
      const size_t r = (size_t)(rowb + j - IC) * NOUT;
      A.Yb[0][r + bcol] = h0[j];
      A.Yb[0][r + bcol + 16] = h1[j];
    }
  }
  __syncthreads();
  if (t < 32) {
    const int row = r0 + t;
    const float s = sred[0][0][t] + sred[1][0][t];
    const float q2 = sred[0][1][t] + sred[1][1][t];
    const float inv = rsqrtf(q2 - s * s * (1.0f / 64.0f));
    if (row < IC) {
      A.summT[nt * 512 + row] = s;
      A.invxT[nt * 512 + row] = inv;
    } else {
      A.syT[0][nt * 128 + (row - IC)] = s;
      A.invyT[0][nt * 128 + (row - IC)] = inv;
    }
  }
}

// ===================== K2: fused round kernel (no a/p materialization) ==========
// Block (k = bid>>3, bt = bid&7 -> XCD), 256 thr. Per round:
//   A: [R>0] stage vsum(16b x 1024) in LDS; per i-tile compute all-16-k' a-dots
//      (in-register) + own-k P; in-lane softmax; D -> LDS.  [R=0] d=1/16 exact.
//   B: hatv MFMA from LDS D + HTb; squash.
//   C: y/vsum bf16 update (coalesced, own k-slice) + y stats.  [R=2] write outp.
template <int R>
__global__ __launch_bounds__(256) void k_round(KArgs A)
{
  __shared__ ushort D[16][520];      // [b][i] bf16 (+8 pad)
  __shared__ ushort vL[16][1032];    // vsum_prev [b][n] (+8 pad), R>0
  __shared__ float red[3][4][16];
  __shared__ float sscale[16];

  const int t = threadIdx.x;
  const int bid = blockIdx.x;
  const int bt = bid & 7, k = bid >> 3;
  const int b0 = bt * 16;
  const int w = t >> 6, L = t & 63, c = L & 15, g = L >> 4;

  const ushort* Ycur = A.Yb[R];

  if (R) {
    const ushort* Vprev = A.Vb[R - 1];
    #pragma unroll
    for (int u = 0; u < 8; ++u) {
      const int id = u * 256 + t;          // 2048 short8v units
      const int b = id >> 7;
      const int col = (id & 127) * 8;
      *(short8v*)&vL[b][col] = *(const short8v*)&Vprev[(size_t)(b0 + b) * 1024 + col];
    }
    __syncthreads();
  }

  // own-k y fragment + pearson y-scalars (lane c = b)
  const short8v yf0 = *(const short8v*)&Ycur[(size_t)(b0 + c) * 1024 + k * 64 + g * 8];
  const short8v yf1 = *(const short8v*)&Ycur[(size_t)(b0 + c) * 1024 + k * 64 + 32 + g * 8];
  const float syb = A.syT[R][k * 128 + b0 + c] * (1.0f / 64.0f);
  const float iyb = A.invyT[R][k * 128 + b0 + c];

  // ---------- phase A ----------
  for (int n = 0; n < 8; ++n) {
    const int i0 = (w * 8 + n) * 16;
    const ushort* hrow = A.Hb + (size_t)(i0 + c) * 1024;
    f32x4 P = {};
    {
      const short8v a0 = *(const short8v*)&hrow[k * 64 + g * 8];
      const short8v a1 = *(const short8v*)&hrow[k * 64 + 32 + g * 8];
      P = MFMA(a0, yf0, P, 0, 0, 0);
      P = MFMA(a1, yf1, P, 0, 0, 0);
    }
    const f32x4 sm4 = *(const f32x4*)&A.summT[(size_t)k * 512 + i0 + 4 * g];
    const f32x4 ix4 = *(const f32x4*)&A.invxT[(size_t)k * 512 + i0 + 4 * g];

    ushort4 dv;
    if (R == 0) {
      dv.x = bf_rne(0.0625f - tanh_fast((P[0] - sm4[0] * syb) * ix4[0] * iyb));
      dv.y = bf_rne(0.0625f - tanh_fast((P[1] - sm4[1] * syb) * ix4[1] * iyb));
      dv.z = bf_rne(0.0625f - tanh_fast((P[2] - sm4[2] * syb) * ix4[2] * iyb));
      dv.w = bf_rne(0.0625f - tanh_fast((P[3] - sm4[3] * syb) * ix4[3] * iyb));
    } else {
      f32x4 aa[16];
      #pragma unroll
      for (int kp = 0; kp < 16; ++kp) aa[kp] = f32x4{0.f, 0.f, 0.f, 0.f};
      #pragma unroll 4
      for (int kp = 0; kp < 16; ++kp) {
        const short8v av0 = *(const short8v*)&hrow[kp * 64 + g * 8];
        const short8v av1 = *(const short8v*)&hrow[kp * 64 + 32 + g * 8];
        const short8v bv0 = *(const short8v*)&vL[c][kp * 64 + g * 8];
        const short8v bv1 = *(const short8v*)&vL[c][kp * 64 + 32 + g * 8];
        aa[kp] = MFMA(av0, bv0, aa[kp], 0, 0, 0);
        aa[kp] = MFMA(av1, bv1, aa[kp], 0, 0, 0);
      }
      #pragma unroll
      for (int j = 0; j < 4; ++j) {
        float mx = -1e30f;
        #pragma unroll
        for (int kp = 0; kp < 16; ++kp) mx = fmaxf(mx, aa[kp][j]);
        float es = 0.f, own = 0.f;
        #pragma unroll
        for (int kp = 0; kp < 16; ++kp) {
          const float e = __expf(aa[kp][j] - mx);
          es += e;
          if (kp == k) own = e;      // kp compile-time, k wave-uniform: no indexing
        }
        const float p = tanh_fast((P[j] - sm4[j] * syb) * ix4[j] * iyb);
        const ushort r = bf_rne(own / es - p);
        if (j == 0) dv.x = r; else if (j == 1) dv.y = r;
        else if (j == 2) dv.z = r; else dv.w = r;
      }
    }
    *(ushort4*)&D[c][i0 + 4 * g] = dv;
  }
  __syncthreads();

  // ---------- phase B: hatv + squash ----------
  // A = D rows (lane c = b), B = HTb rows (d = w*16+c); C: col(c)=d, row(4g+j)=b.
  f32x4 hacc = {};
  #pragma unroll 4
  for (int it = 0; it < 16; ++it) {
    const short8v Af = *(const short8v*)&D[c][it * 32 + g * 8];
    const short8v Bf = *(const short8v*)
        &A.HTb[(size_t)(k * 64 + w * 16 + c) * 512 + it * 32 + g * 8];
    hacc = MFMA(Af, Bf, hacc, 0, 0, 0);
  }
  float sq[4];
  #pragma unroll
  for (int j = 0; j < 4; ++j) {
    sq[j] = hacc[j] * hacc[j];
    #pragma unroll
    for (int off = 1; off < 16; off <<= 1) sq[j] += __shfl_xor(sq[j], off);
  }
  if (c == 0) {
    #pragma unroll
    for (int j = 0; j < 4; ++j) red[0][w][4 * g + j] = sq[j];
  }
  __syncthreads();
  if (t < 16) {
    const float s = red[0][0][t] + red[0][1][t] + red[0][2][t] + red[0][3][t];
    sscale[t] = (s / (1.0f + s)) * rsqrtf(s + 1e-8f);
  }
  __syncthreads();

  // ---------- phase C ----------
  const int d = w * 16 + c;
  if (R == 2) {
    #pragma unroll
    for (int j = 0; j < 4; ++j)
      A.outp[(size_t)(b0 + 4 * g + j) * 1024 + k * 64 + d] =
          hacc[j] * sscale[4 * g + j];
  } else {
    float s1[4], s2[4];
    #pragma unroll
    for (int j = 0; j < 4; ++j) {
      const int b = 4 * g + j;
      const size_t gi = (size_t)(b0 + b) * 1024 + (size_t)k * 64 + d;
      const float v = hacc[j] * sscale[b];
      const float vs = (R == 0) ? v : (bf_f(vL[b][k * 64 + d]) + v);
      A.Vb[R][gi] = bf_rne(vs);
      const float yn = (bf_f(Ycur[gi]) + v) * 0.5f;
      const ushort ynb = bf_rne(yn);
      A.Yb[R + 1][gi] = ynb;
      const float ynr = bf_f(ynb);
      s1[j] = ynr; s2[j] = ynr * ynr;
    }
    #pragma unroll
    for (int j = 0; j < 4; ++j) {
      #pragma unroll
      for (int off = 1; off < 16; off <<= 1) {
        s1[j] += __shfl_xor(s1[j], off);
        s2[j] += __shfl_xor(s2[j], off);
      }
    }
    if (c == 0) {
      #pragma unroll
      for (int j = 0; j < 4; ++j) {
        red[1][w][4 * g + j] = s1[j];
        red[2][w][4 * g + j] = s2[j];
      }
    }
    __syncthreads();
    if (t < 16) {
      const float s = red[1][0][t] + red[1][1][t] + red[1][2][t] + red[1][3][t];
      const float q2 = red[2][0][t] + red[2][1][t] + red[2][2][t] + red[2][3][t];
      A.syT[R + 1][k * 128 + b0 + t] = s;
      A.invyT[R + 1][k * 128 + b0 + t] = rsqrtf(q2 - s * s * (1.0f / 64.0f));
    }
  }
}

// ===================== launch =====================
extern "C" void kernel_launch(void* const* d_in, const int* in_sizes, int n_in,
                              void* d_out, int out_size, void* d_ws, size_t ws_size,
                              hipStream_t stream) {
  char* w = (char*)d_ws;
  KArgs A;
  A.m  = (const float*)d_in[0];
  A.q  = (const float*)d_in[1];
  A.Ww = (const float*)d_in[2];
  A.Wb = (const float*)d_in[3];
  A.Hb     = (ushort*)(w + 0);          // 1048576
  A.HTb    = (ushort*)(w + 1048576);    // 1048576
  A.Yb[0]  = (ushort*)(w + 2097152);    // 262144 each
  A.Yb[1]  = (ushort*)(w + 2359296);
  A.Yb[2]  = (ushort*)(w + 2621440);
  A.Vb[0]  = (ushort*)(w + 2883584);    // 262144 each
  A.Vb[1]  = (ushort*)(w + 3145728);
  A.summT  = (float*)(w + 3407872);     // 32768
  A.invxT  = (float*)(w + 3440640);     // 32768
  A.syT[0]   = (float*)(w + 3473408);   // 8192 each
  A.syT[1]   = (float*)(w + 3481600);
  A.syT[2]   = (float*)(w + 3489792);
  A.invyT[0] = (float*)(w + 3497984);
  A.invyT[1] = (float*)(w + 3506176);
  A.invyT[2] = (float*)(w + 3514368);
  A.outp = (float*)d_out;

  k_gemm<<<320, 256, 0, stream>>>(A);
  k_round<0><<<128, 256, 0, stream>>>(A);
  k_round<1><<<128, 256, 0, stream>>>(A);
  k_round<2><<<128, 256, 0, stream>>>(A);
}

// Round 13
// 101.089 us; speedup vs baseline: 2.0223x; 2.0223x over previous
//
#include <hip/hip_runtime.h>
#include <hip/hip_bf16.h>
#include <cstdint>
#include <cstddef>

#define IC 512     // in_caps
#define IDM 768    // in_dim
#define KC 16      // num_caps
#define NB 128     // batch
#define NOUT 1024  // KC*DC

typedef __attribute__((ext_vector_type(8))) short short8v;
typedef __attribute__((ext_vector_type(4))) float f32x4;

#define MFMA __builtin_amdgcn_mfma_f32_16x16x32_bf16

static __device__ __forceinline__ unsigned fbits(float x) {
  union { float f; unsigned u; } z; z.f = x; return z.u;
}
static __device__ __forceinline__ float bf_f(ushort u) {
  union { float f; unsigned u32; } z; z.u32 = ((unsigned)u) << 16; return z.f;
}
static __device__ __forceinline__ ushort bf_rne(float x) {
  __hip_bfloat16 h = __float2bfloat16(x);
  return *reinterpret_cast<ushort*>(&h);
}
// truncation hi/lo split (GEMM input path only)
static __device__ __forceinline__ void split2(float x, ushort& h, ushort& l) {
  h = (ushort)(fbits(x) >> 16);
  const float r = x - bf_f(h);
  l = (ushort)(fbits(r) >> 16);
}
static __device__ __forceinline__ void split8(const float* p, short8v& h, short8v& l) {
  const float4 x0 = *(const float4*)p;
  const float4 x1 = *(const float4*)(p + 4);
  const float xs[8] = {x0.x, x0.y, x0.z, x0.w, x1.x, x1.y, x1.z, x1.w};
  #pragma unroll
  for (int j = 0; j < 8; ++j) {
    ushort hh, ll; split2(xs[j], hh, ll);
    h[j] = (short)hh; l[j] = (short)ll;
  }
}
static __device__ __forceinline__ float tanh_fast(float x) {
  const float e2 = __expf(2.0f * x);
  return 1.0f - 2.0f / (e2 + 1.0f);
}

struct KArgs {
  const float *m, *q, *Ww, *Wb;
  ushort *Hb, *HTb;          // hat_m bf16 [i][n] and [n][i]
  ushort *Yb0, *Yb1, *Vb0;   // bf16 [b][1024]
  float *pP;                 // p  f32 [b][k][i]  (plane (b,k) owned by block (k,bt))
  float *aB[2];              // a  f32 [b][k][i]  double-buffered across rounds
  float *summT, *invxT;      // H row stats (of bf16 H): [k][i]
  float *syT0, *invyT0;      // y0 stats: [k][b]
  float *outp;
};

// ===================== K1: GEMM (hi/lo f32-accurate) + bf16 epilogue ============
// Verbatim R9/R11/R12-verified kernel.
__global__ __launch_bounds__(256) void k_gemm(KArgs A)
{
  __shared__ float sred[2][2][32];
  const int t = threadIdx.x;
  const int bid = blockIdx.x;
  const int region = bid & 7, idx = bid >> 3;
  const int rt = (region & 1) * 10 + (idx % 10);
  const int nt = (region >> 1) * 4 + (idx / 10);
  const int w = t >> 6, L = t & 63, c = L & 15, g = L >> 4;
  const int wr = w >> 1, wc = w & 1;
  const int r0 = rt * 32, n0 = nt * 64;
  const int arow = r0 + wr * 16 + c;
  const int bcol = n0 + wc * 32 + c;
  const float* asrc = (arow < IC) ? (A.m + (size_t)arow * IDM)
                                  : (A.q + (size_t)(arow - IC) * IDM);
  const float* b0src = A.Ww + (size_t)bcol * IDM;
  const float* b1src = A.Ww + (size_t)(bcol + 16) * IDM;

  f32x4 acc0 = {}, acc1 = {};
  #pragma unroll 2
  for (int kb = 0; kb < IDM; kb += 32) {
    short8v ah, al, bh0, bl0, bh1, bl1;
    split8(asrc + kb + g * 8, ah, al);
    split8(b0src + kb + g * 8, bh0, bl0);
    split8(b1src + kb + g * 8, bh1, bl1);
    acc0 = MFMA(ah, bh0, acc0, 0, 0, 0);
    acc0 = MFMA(ah, bl0, acc0, 0, 0, 0);
    acc0 = MFMA(al, bh0, acc0, 0, 0, 0);
    acc1 = MFMA(ah, bh1, acc1, 0, 0, 0);
    acc1 = MFMA(ah, bl1, acc1, 0, 0, 0);
    acc1 = MFMA(al, bh1, acc1, 0, 0, 0);
  }

  const float bias0 = A.Wb[bcol];
  const float bias1 = A.Wb[bcol + 16];
  ushort h0[4], h1[4];
  float r0s[4], r1s[4];
  #pragma unroll
  for (int j = 0; j < 4; ++j) {
    h0[j] = bf_rne(acc0[j] + bias0); r0s[j] = bf_f(h0[j]);
    h1[j] = bf_rne(acc1[j] + bias1); r1s[j] = bf_f(h1[j]);
  }

  #pragma unroll
  for (int j = 0; j < 4; ++j) {
    float s = r0s[j] + r1s[j];
    float q2 = r0s[j] * r0s[j] + r1s[j] * r1s[j];
    #pragma unroll
    for (int off = 1; off < 16; off <<= 1) {
      s += __shfl_xor(s, off);
      q2 += __shfl_xor(q2, off);
    }
    if (c == 0) {
      sred[wc][0][wr * 16 + 4 * g + j] = s;
      sred[wc][1][wr * 16 + 4 * g + j] = q2;
    }
  }

  const int rowb = r0 + wr * 16 + 4 * g;
  if (rowb < IC) {
    #pragma unroll
    for (int j = 0; j < 4; ++j) {
      const size_t r = (size_t)(rowb + j) * NOUT;
      A.Hb[r + bcol] = h0[j];
      A.Hb[r + bcol + 16] = h1[j];
    }
    *(ushort4*)&A.HTb[(size_t)bcol * 512 + rowb] = make_ushort4(h0[0], h0[1], h0[2], h0[3]);
    *(ushort4*)&A.HTb[(size_t)(bcol + 16) * 512 + rowb] = make_ushort4(h1[0], h1[1], h1[2], h1[3]);
  } else {
    #pragma unroll
    for (int j = 0; j < 4; ++j) {
      const size_t r = (size_t)(rowb + j - IC) * NOUT;
      A.Yb0[r + bcol] = h0[j];
      A.Yb0[r + bcol + 16] = h1[j];
    }
  }
  __syncthreads();
  if (t < 32) {
    const int row = r0 + t;
    const float s = sred[0][0][t] + sred[1][0][t];
    const float q2 = sred[0][1][t] + sred[1][1][t];
    const float inv = rsqrtf(q2 - s * s * (1.0f / 64.0f));
    if (row < IC) {
      A.summT[nt * 512 + row] = s;
      A.invxT[nt * 512 + row] = inv;
    } else {
      A.syT0[nt * 128 + (row - IC)] = s;
      A.invyT0[nt * 128 + (row - IC)] = inv;
    }
  }
}

// ===================== K2: fused round kernel =====================
// Block (k = bid>>3, bt = bid&7 -> XCD), 256 thr.
//  A: [R=0] own-k P MFMA (d=1/16 exact)  [R12-verified]
//     [R>0] coalesced softmax: wave=4 b's, lanes sweep i; a from aB[R-1], p from pP.
//  B: hatv MFMA (LDS D + HTb) + squash  [R12-verified]
//  C: [R<2] y/v update + stats; own-k next-round p,a MFMA -> pP/aB[R] ([b][k][i],
//     64B-contiguous per plane)  [R11-verified math]. [R=2] write outp.
template <int R>
__global__ __launch_bounds__(256) void k_round(KArgs A)
{
  __shared__ ushort D[16][520];      // [b][i] bf16 (+8 pad)
  __shared__ ushort yL[16][72];      // y_new own-k slice [b][d]
  __shared__ ushort vL[16][72];      // vsum_new own-k slice
  __shared__ float red[3][4][16];
  __shared__ float sscale[16], syL[16], iyL[16];

  const int t = threadIdx.x;
  const int bid = blockIdx.x;
  const int bt = bid & 7, k = bid >> 3;
  const int b0 = bt * 16;
  const int w = t >> 6, L = t & 63, c = L & 15, g = L >> 4;

  // ---------- phase A: D into LDS ----------
  if (R == 0) {
    const short8v yf0 = *(const short8v*)&A.Yb0[(size_t)(b0 + c) * 1024 + k * 64 + g * 8];
    const short8v yf1 = *(const short8v*)&A.Yb0[(size_t)(b0 + c) * 1024 + k * 64 + 32 + g * 8];
    const float syb = A.syT0[k * 128 + b0 + c] * (1.0f / 64.0f);
    const float iyb = A.invyT0[k * 128 + b0 + c];
    #pragma unroll 2
    for (int n = 0; n < 8; ++n) {
      const int i0 = (w * 8 + n) * 16;
      const ushort* hrow = A.Hb + (size_t)(i0 + c) * 1024;
      f32x4 P = {};
      {
        const short8v a0 = *(const short8v*)&hrow[k * 64 + g * 8];
        const short8v a1 = *(const short8v*)&hrow[k * 64 + 32 + g * 8];
        P = MFMA(a0, yf0, P, 0, 0, 0);
        P = MFMA(a1, yf1, P, 0, 0, 0);
      }
      const f32x4 sm4 = *(const f32x4*)&A.summT[(size_t)k * 512 + i0 + 4 * g];
      const f32x4 ix4 = *(const f32x4*)&A.invxT[(size_t)k * 512 + i0 + 4 * g];
      ushort4 dv;
      dv.x = bf_rne(0.0625f - tanh_fast((P[0] - sm4[0] * syb) * ix4[0] * iyb));
      dv.y = bf_rne(0.0625f - tanh_fast((P[1] - sm4[1] * syb) * ix4[1] * iyb));
      dv.z = bf_rne(0.0625f - tanh_fast((P[2] - sm4[2] * syb) * ix4[2] * iyb));
      dv.w = bf_rne(0.0625f - tanh_fast((P[3] - sm4[3] * syb) * ix4[3] * iyb));
      *(ushort4*)&D[c][i0 + 4 * g] = dv;
    }
  } else {
    // coalesced in-lane softmax; a planes from previous round's phase C (same bt/XCD)
    const float* aprev = A.aB[R - 1];
    #pragma unroll
    for (int bb = 0; bb < 4; ++bb) {
      const int b = w * 4 + bb;
      const float* abase = aprev + (size_t)(b0 + b) * 8192;
      const float* pbase = A.pP + (size_t)(b0 + b) * 8192 + (size_t)k * 512;
      #pragma unroll 2
      for (int ii = 0; ii < 8; ++ii) {
        const int i = ii * 64 + L;
        float av[16];
        float mx = -1e30f;
        #pragma unroll
        for (int kk = 0; kk < 16; ++kk) {
          av[kk] = abase[(size_t)kk * 512 + i];
          mx = fmaxf(mx, av[kk]);
        }
        float es = 0.f, own = 0.f;
        #pragma unroll
        for (int kk = 0; kk < 16; ++kk) {
          const float e = __expf(av[kk] - mx);
          es += e;
          if (kk == k) own = e;     // kk compile-time, k wave-uniform
        }
        D[b][i] = bf_rne(own / es - pbase[i]);
      }
    }
  }
  __syncthreads();

  // ---------- phase B: hatv + squash  [R12-verified] ----------
  f32x4 hacc = {};
  #pragma unroll 4
  for (int it = 0; it < 16; ++it) {
    const short8v Af = *(const short8v*)&D[c][it * 32 + g * 8];
    const short8v Bf = *(const short8v*)
        &A.HTb[(size_t)(k * 64 + w * 16 + c) * 512 + it * 32 + g * 8];
    hacc = MFMA(Af, Bf, hacc, 0, 0, 0);
  }
  float sq[4];
  #pragma unroll
  for (int j = 0; j < 4; ++j) {
    sq[j] = hacc[j] * hacc[j];
    #pragma unroll
    for (int off = 1; off < 16; off <<= 1) sq[j] += __shfl_xor(sq[j], off);
  }
  if (c == 0) {
    #pragma unroll
    for (int j = 0; j < 4; ++j) red[0][w][4 * g + j] = sq[j];
  }
  __syncthreads();
  if (t < 16) {
    const float s = red[0][0][t] + red[0][1][t] + red[0][2][t] + red[0][3][t];
    sscale[t] = (s / (1.0f + s)) * rsqrtf(s + 1e-8f);
  }
  __syncthreads();

  // ---------- phase C ----------
  const int d = w * 16 + c;
  if (R == 2) {
    #pragma unroll
    for (int j = 0; j < 4; ++j)
      A.outp[(size_t)(b0 + 4 * g + j) * 1024 + k * 64 + d] =
          hacc[j] * sscale[4 * g + j];
  } else {
    // y/v own-k-slice update (bf16 chains, R11-verified)
    float s1[4], s2[4];
    #pragma unroll
    for (int j = 0; j < 4; ++j) {
      const int b = 4 * g + j;
      const size_t gi = (size_t)(b0 + b) * 1024 + (size_t)k * 64 + d;
      const float v = hacc[j] * sscale[b];
      const float vs = (R == 0) ? v : (bf_f(A.Vb0[gi]) + v);
      const ushort vsb = bf_rne(vs);
      const float yo = bf_f((R == 0 ? A.Yb0 : A.Yb1)[gi]);
      const ushort ynb = bf_rne((yo + v) * 0.5f);
      if (R == 0) { A.Vb0[gi] = vsb; A.Yb1[gi] = ynb; }
      vL[b][d] = vsb;
      yL[b][d] = ynb;
      const float ynr = bf_f(ynb);
      s1[j] = ynr; s2[j] = ynr * ynr;
    }
    #pragma unroll
    for (int j = 0; j < 4; ++j) {
      #pragma unroll
      for (int off = 1; off < 16; off <<= 1) {
        s1[j] += __shfl_xor(s1[j], off);
        s2[j] += __shfl_xor(s2[j], off);
      }
    }
    if (c == 0) {
      #pragma unroll
      for (int j = 0; j < 4; ++j) {
        red[1][w][4 * g + j] = s1[j];
        red[2][w][4 * g + j] = s2[j];
      }
    }
    __syncthreads();
    if (t < 16) {
      const float s = red[1][0][t] + red[1][1][t] + red[1][2][t] + red[1][3][t];
      const float q2 = red[2][0][t] + red[2][1][t] + red[2][2][t] + red[2][3][t];
      syL[t] = s;
      iyL[t] = rsqrtf(q2 - s * s * (1.0f / 64.0f));
    }
    __syncthreads();

    // next-round own-k p,a planes (coalesced 64B-chunk writes)  [R11-verified math]
    const float syb = syL[c] * (1.0f / 64.0f);
    const float iyb = iyL[c];
    float* pw = A.pP + (size_t)(b0 + c) * 8192 + (size_t)k * 512;
    float* aw = A.aB[R] + (size_t)(b0 + c) * 8192 + (size_t)k * 512;
    #pragma unroll 2
    for (int n = 0; n < 8; ++n) {
      const int i0 = (w * 8 + n) * 16;
      f32x4 P = {}, Aa = {};
      #pragma unroll
      for (int ks = 0; ks < 2; ++ks) {
        const short8v Af = *(const short8v*)
            &A.Hb[(size_t)(i0 + c) * 1024 + k * 64 + ks * 32 + g * 8];
        const short8v By = *(const short8v*)&yL[c][ks * 32 + g * 8];
        const short8v Bv = *(const short8v*)&vL[c][ks * 32 + g * 8];
        P = MFMA(Af, By, P, 0, 0, 0);
        Aa = MFMA(Af, Bv, Aa, 0, 0, 0);
      }
      const f32x4 sm4 = *(const f32x4*)&A.summT[(size_t)k * 512 + i0 + 4 * g];
      const f32x4 ix4 = *(const f32x4*)&A.invxT[(size_t)k * 512 + i0 + 4 * g];
      f32x4 p4;
      #pragma unroll
      for (int j = 0; j < 4; ++j)
        p4[j] = tanh_fast((P[j] - sm4[j] * syb) * ix4[j] * iyb);
      *(f32x4*)&pw[i0 + 4 * g] = p4;
      *(f32x4*)&aw[i0 + 4 * g] = Aa;
    }
  }
}

// ===================== launch =====================
extern "C" void kernel_launch(void* const* d_in, const int* in_sizes, int n_in,
                              void* d_out, int out_size, void* d_ws, size_t ws_size,
                              hipStream_t stream) {
  char* w = (char*)d_ws;
  KArgs A;
  A.m  = (const float*)d_in[0];
  A.q  = (const float*)d_in[1];
  A.Ww = (const float*)d_in[2];
  A.Wb = (const float*)d_in[3];
  A.Hb     = (ushort*)(w + 0);          // 1048576
  A.HTb    = (ushort*)(w + 1048576);    // 1048576
  A.Yb0    = (ushort*)(w + 2097152);    // 262144
  A.Yb1    = (ushort*)(w + 2359296);    // 262144
  A.Vb0    = (ushort*)(w + 2621440);    // 262144
  A.pP     = (float*)(w + 2883584);     // 4194304
  A.aB[0]  = (float*)(w + 7077888);     // 4194304
  A.aB[1]  = (float*)(w + 11272192);    // 4194304
  A.summT  = (float*)(w + 15466496);    // 32768
  A.invxT  = (float*)(w + 15499264);    // 32768
  A.syT0   = (float*)(w + 15532032);    // 8192
  A.invyT0 = (float*)(w + 15540224);    // 8192
  A.outp = (float*)d_out;

  k_gemm<<<320, 256, 0, stream>>>(A);
  k_round<0><<<128, 256, 0, stream>>>(A);
  k_round<1><<<128, 256, 0, stream>>>(A);
  k_round<2><<<128, 256, 0, stream>>>(A);
}

// Round 14
// 84.293 us; speedup vs baseline: 2.4252x; 1.1993x over previous
//
#include <hip/hip_runtime.h>
#include <hip/hip_bf16.h>
#include <cstdint>
#include <cstddef>

#define IC 512     // in_caps
#define IDM 768    // in_dim
#define KC 16      // num_caps
#define NB 128     // batch
#define NOUT 1024  // KC*DC

typedef __attribute__((ext_vector_type(8))) short short8v;
typedef __attribute__((ext_vector_type(4))) float f32x4;

#define MFMA __builtin_amdgcn_mfma_f32_16x16x32_bf16

static __device__ __forceinline__ unsigned fbits(float x) {
  union { float f; unsigned u; } z; z.f = x; return z.u;
}
static __device__ __forceinline__ float bf_f(ushort u) {
  union { float f; unsigned u32; } z; z.u32 = ((unsigned)u) << 16; return z.f;
}
static __device__ __forceinline__ ushort bf_rne(float x) {
  __hip_bfloat16 h = __float2bfloat16(x);
  return *reinterpret_cast<ushort*>(&h);
}
// truncation hi/lo split (GEMM input path only)
static __device__ __forceinline__ void split2(float x, ushort& h, ushort& l) {
  h = (ushort)(fbits(x) >> 16);
  const float r = x - bf_f(h);
  l = (ushort)(fbits(r) >> 16);
}
static __device__ __forceinline__ void split8(const float* p, short8v& h, short8v& l) {
  const float4 x0 = *(const float4*)p;
  const float4 x1 = *(const float4*)(p + 4);
  const float xs[8] = {x0.x, x0.y, x0.z, x0.w, x1.x, x1.y, x1.z, x1.w};
  #pragma unroll
  for (int j = 0; j < 8; ++j) {
    ushort hh, ll; split2(xs[j], hh, ll);
    h[j] = (short)hh; l[j] = (short)ll;
  }
}
static __device__ __forceinline__ float tanh_fast(float x) {
  const float e2 = __expf(2.0f * x);
  return 1.0f - 2.0f / (e2 + 1.0f);
}

struct KArgs {
  const float *m, *q, *Ww, *Wb;
  ushort *Hb, *HTb;          // hat_m bf16 [i][n] and [n][i]
  ushort *Yb0, *Yb1, *Vb0;   // bf16 [b][1024]
  float *pP;                 // p f32 [b][k][i] (plane (b,k) owned by block (k,bt))
  float *aB[2];              // a f32 [b][k][i], double-buffered
  float *summT, *invxT;      // H row stats (of bf16 H): [k][i]
  float *syT0, *invyT0;      // y0 stats: [k][b]
  float *outp;
};

// ===================== K1: GEMM (hi/lo f32-accurate) + bf16 epilogue ============
// Verbatim R9..R13-verified kernel.
__global__ __launch_bounds__(256) void k_gemm(KArgs A)
{
  __shared__ float sred[2][2][32];
  const int t = threadIdx.x;
  const int bid = blockIdx.x;
  const int region = bid & 7, idx = bid >> 3;
  const int rt = (region & 1) * 10 + (idx % 10);
  const int nt = (region >> 1) * 4 + (idx / 10);
  const int w = t >> 6, L = t & 63, c = L & 15, g = L >> 4;
  const int wr = w >> 1, wc = w & 1;
  const int r0 = rt * 32, n0 = nt * 64;
  const int arow = r0 + wr * 16 + c;
  const int bcol = n0 + wc * 32 + c;
  const float* asrc = (arow < IC) ? (A.m + (size_t)arow * IDM)
                                  : (A.q + (size_t)(arow - IC) * IDM);
  const float* b0src = A.Ww + (size_t)bcol * IDM;
  const float* b1src = A.Ww + (size_t)(bcol + 16) * IDM;

  f32x4 acc0 = {}, acc1 = {};
  #pragma unroll 2
  for (int kb = 0; kb < IDM; kb += 32) {
    short8v ah, al, bh0, bl0, bh1, bl1;
    split8(asrc + kb + g * 8, ah, al);
    split8(b0src + kb + g * 8, bh0, bl0);
    split8(b1src + kb + g * 8, bh1, bl1);
    acc0 = MFMA(ah, bh0, acc0, 0, 0, 0);
    acc0 = MFMA(ah, bl0, acc0, 0, 0, 0);
    acc0 = MFMA(al, bh0, acc0, 0, 0, 0);
    acc1 = MFMA(ah, bh1, acc1, 0, 0, 0);
    acc1 = MFMA(ah, bl1, acc1, 0, 0, 0);
    acc1 = MFMA(al, bh1, acc1, 0, 0, 0);
  }

  const float bias0 = A.Wb[bcol];
  const float bias1 = A.Wb[bcol + 16];
  ushort h0[4], h1[4];
  float r0s[4], r1s[4];
  #pragma unroll
  for (int j = 0; j < 4; ++j) {
    h0[j] = bf_rne(acc0[j] + bias0); r0s[j] = bf_f(h0[j]);
    h1[j] = bf_rne(acc1[j] + bias1); r1s[j] = bf_f(h1[j]);
  }

  #pragma unroll
  for (int j = 0; j < 4; ++j) {
    float s = r0s[j] + r1s[j];
    float q2 = r0s[j] * r0s[j] + r1s[j] * r1s[j];
    #pragma unroll
    for (int off = 1; off < 16; off <<= 1) {
      s += __shfl_xor(s, off);
      q2 += __shfl_xor(q2, off);
    }
    if (c == 0) {
      sred[wc][0][wr * 16 + 4 * g + j] = s;
      sred[wc][1][wr * 16 + 4 * g + j] = q2;
    }
  }

  const int rowb = r0 + wr * 16 + 4 * g;
  if (rowb < IC) {
    #pragma unroll
    for (int j = 0; j < 4; ++j) {
      const size_t r = (size_t)(rowb + j) * NOUT;
      A.Hb[r + bcol] = h0[j];
      A.Hb[r + bcol + 16] = h1[j];
    }
    *(ushort4*)&A.HTb[(size_t)bcol * 512 + rowb] = make_ushort4(h0[0], h0[1], h0[2], h0[3]);
    *(ushort4*)&A.HTb[(size_t)(bcol + 16) * 512 + rowb] = make_ushort4(h1[0], h1[1], h1[2], h1[3]);
  } else {
    #pragma unroll
    for (int j = 0; j < 4; ++j) {
      const size_t r = (size_t)(rowb + j - IC) * NOUT;
      A.Yb0[r + bcol] = h0[j];
      A.Yb0[r + bcol + 16] = h1[j];
    }
  }
  __syncthreads();
  if (t < 32) {
    const int row = r0 + t;
    const float s = sred[0][0][t] + sred[1][0][t];
    const float q2 = sred[0][1][t] + sred[1][1][t];
    const float inv = rsqrtf(q2 - s * s * (1.0f / 64.0f));
    if (row < IC) {
      A.summT[nt * 512 + row] = s;
      A.invxT[nt * 512 + row] = inv;
    } else {
      A.syT0[nt * 128 + (row - IC)] = s;
      A.invyT0[nt * 128 + (row - IC)] = inv;
    }
  }
}

// ===================== K2: fused round kernel (256 blocks, 8 b's each) ==========
// Block (k = bid>>4, bt = bid&15 -> XCD bt%8), 256 thr.
//  A: [R=0] own-k P MFMA (B cols 0-7 = y0, 8-15 zero), d=1/16 exact.
//     [R>0] coalesced no-max softmax from aB[R-1] + pP -> D (LDS).
//  B: hatv MFMA (D rows 0-7) + squash.
//  C: [R<2] y/v own-k update + stats; ONE packed MFMA (B cols 0-7=y_new,
//     8-15=v_new) -> p (tanh'd, cols 0-7) and a (cols 8-15) planes [b][k][i].
//     [R=2] write outp.
template <int R>
__global__ __launch_bounds__(256) void k_round(KArgs A)
{
  __shared__ ushort D[8][520];     // [b][i] bf16 (+8 pad)
  __shared__ ushort yL[8][72];     // y_new own-k slice [b][d]
  __shared__ ushort vL[8][72];     // vsum_new own-k slice
  __shared__ float red[3][4][16];
  __shared__ float sscale[16], syL[16], iyL[16];

  const int t = threadIdx.x;
  const int bid = blockIdx.x;
  const int bt = bid & 15, k = bid >> 4;
  const int b0 = bt * 8;
  const int w = t >> 6, L = t & 63, c = L & 15, g = L >> 4;
  const int cb = c & 7;
  const short8v zfrag = {};

  // ---------- phase A: D into LDS ----------
  if (R == 0) {
    const short8v y0a = *(const short8v*)&A.Yb0[(size_t)(b0 + cb) * 1024 + k * 64 + g * 8];
    const short8v y0b = *(const short8v*)&A.Yb0[(size_t)(b0 + cb) * 1024 + k * 64 + 32 + g * 8];
    const short8v yf0 = (c < 8) ? y0a : zfrag;
    const short8v yf1 = (c < 8) ? y0b : zfrag;
    const float syb = A.syT0[k * 128 + b0 + cb] * (1.0f / 64.0f);
    const float iyb = A.invyT0[k * 128 + b0 + cb];
    #pragma unroll 2
    for (int n = 0; n < 8; ++n) {
      const int i0 = (w * 8 + n) * 16;
      const ushort* hrow = A.Hb + (size_t)(i0 + c) * 1024;
      f32x4 P = {};
      {
        const short8v a0 = *(const short8v*)&hrow[k * 64 + g * 8];
        const short8v a1 = *(const short8v*)&hrow[k * 64 + 32 + g * 8];
        P = MFMA(a0, yf0, P, 0, 0, 0);
        P = MFMA(a1, yf1, P, 0, 0, 0);
      }
      if (c < 8) {
        const f32x4 sm4 = *(const f32x4*)&A.summT[(size_t)k * 512 + i0 + 4 * g];
        const f32x4 ix4 = *(const f32x4*)&A.invxT[(size_t)k * 512 + i0 + 4 * g];
        ushort4 dv;
        dv.x = bf_rne(0.0625f - tanh_fast((P[0] - sm4[0] * syb) * ix4[0] * iyb));
        dv.y = bf_rne(0.0625f - tanh_fast((P[1] - sm4[1] * syb) * ix4[1] * iyb));
        dv.z = bf_rne(0.0625f - tanh_fast((P[2] - sm4[2] * syb) * ix4[2] * iyb));
        dv.w = bf_rne(0.0625f - tanh_fast((P[3] - sm4[3] * syb) * ix4[3] * iyb));
        *(ushort4*)&D[c][i0 + 4 * g] = dv;
      }
    }
  } else {
    // no-max softmax (|a| bounded ~14): wave w -> b's {2w, 2w+1}
    const float* aprev = A.aB[R - 1];
    #pragma unroll
    for (int bb = 0; bb < 2; ++bb) {
      const int b = w * 2 + bb;
      const float* abase = aprev + (size_t)(b0 + b) * 8192;
      const float* pbase = A.pP + (size_t)(b0 + b) * 8192 + (size_t)k * 512;
      #pragma unroll 2
      for (int ii = 0; ii < 8; ++ii) {
        const int i = ii * 64 + L;
        float es = 0.f, own = 0.f;
        #pragma unroll
        for (int kk = 0; kk < 16; ++kk) {
          const float e = __expf(abase[(size_t)kk * 512 + i]);
          es += e;
          if (kk == k) own = e;    // kk compile-time, k wave-uniform
        }
        D[b][i] = bf_rne(own / es - pbase[i]);
      }
    }
  }
  __syncthreads();

  // ---------- phase B: hatv + squash ----------
  // A = D rows (b via lane c, rows 8-15 zero), B = HTb rows (d = w*16+c);
  // C: col(c)=d, row(4g+j)=b (valid rows 0-7 i.e. g<2).
  f32x4 hacc = {};
  #pragma unroll 4
  for (int it = 0; it < 16; ++it) {
    const short8v dldr = *(const short8v*)&D[cb][it * 32 + g * 8];
    const short8v Af = (c < 8) ? dldr : zfrag;
    const short8v Bf = *(const short8v*)
        &A.HTb[(size_t)(k * 64 + w * 16 + c) * 512 + it * 32 + g * 8];
    hacc = MFMA(Af, Bf, hacc, 0, 0, 0);
  }
  float sq[4];
  #pragma unroll
  for (int j = 0; j < 4; ++j) {
    sq[j] = hacc[j] * hacc[j];
    #pragma unroll
    for (int off = 1; off < 16; off <<= 1) sq[j] += __shfl_xor(sq[j], off);
  }
  if (c == 0) {
    #pragma unroll
    for (int j = 0; j < 4; ++j) red[0][w][4 * g + j] = sq[j];
  }
  __syncthreads();
  if (t < 16) {
    const float s = red[0][0][t] + red[0][1][t] + red[0][2][t] + red[0][3][t];
    sscale[t] = (s / (1.0f + s)) * rsqrtf(s + 1e-8f);
  }
  __syncthreads();

  // ---------- phase C ----------
  const int d = w * 16 + c;
  if (R == 2) {
    if (g < 2) {
      #pragma unroll
      for (int j = 0; j < 4; ++j)
        A.outp[(size_t)(b0 + 4 * g + j) * 1024 + k * 64 + d] =
            hacc[j] * sscale[4 * g + j];
    }
  } else {
    float s1[4] = {0.f, 0.f, 0.f, 0.f}, s2[4] = {0.f, 0.f, 0.f, 0.f};
    if (g < 2) {
      #pragma unroll
      for (int j = 0; j < 4; ++j) {
        const int b = 4 * g + j;
        const size_t gi = (size_t)(b0 + b) * 1024 + (size_t)k * 64 + d;
        const float v = hacc[j] * sscale[b];
        const float vs = (R == 0) ? v : (bf_f(A.Vb0[gi]) + v);
        const ushort vsb = bf_rne(vs);
        const float yo = bf_f((R == 0 ? A.Yb0 : A.Yb1)[gi]);
        const ushort ynb = bf_rne((yo + v) * 0.5f);
        if (R == 0) { A.Vb0[gi] = vsb; A.Yb1[gi] = ynb; }
        vL[b][d] = vsb;
        yL[b][d] = ynb;
        const float ynr = bf_f(ynb);
        s1[j] = ynr; s2[j] = ynr * ynr;
      }
    }
    #pragma unroll
    for (int j = 0; j < 4; ++j) {
      #pragma unroll
      for (int off = 1; off < 16; off <<= 1) {
        s1[j] += __shfl_xor(s1[j], off);
        s2[j] += __shfl_xor(s2[j], off);
      }
    }
    if (c == 0) {
      #pragma unroll
      for (int j = 0; j < 4; ++j) {
        red[1][w][4 * g + j] = s1[j];
        red[2][w][4 * g + j] = s2[j];
      }
    }
    __syncthreads();
    if (t < 16) {
      const float s = red[1][0][t] + red[1][1][t] + red[1][2][t] + red[1][3][t];
      const float q2 = red[2][0][t] + red[2][1][t] + red[2][2][t] + red[2][3][t];
      syL[t] = s;
      iyL[t] = rsqrtf(q2 - s * s * (1.0f / 64.0f));
    }
    __syncthreads();

    // packed next-round p,a: B cols 0-7 = y_new, 8-15 = v_new
    const float syb = syL[cb] * (1.0f / 64.0f);
    const float iyb = iyL[cb];
    #pragma unroll 2
    for (int n = 0; n < 8; ++n) {
      const int i0 = (w * 8 + n) * 16;
      f32x4 acc = {};
      #pragma unroll
      for (int ks = 0; ks < 2; ++ks) {
        const short8v Af = *(const short8v*)
            &A.Hb[(size_t)(i0 + c) * 1024 + k * 64 + ks * 32 + g * 8];
        const short8v By = *(const short8v*)&yL[cb][ks * 32 + g * 8];
        const short8v Bv = *(const short8v*)&vL[cb][ks * 32 + g * 8];
        const short8v Bf = (c < 8) ? By : Bv;
        acc = MFMA(Af, Bf, acc, 0, 0, 0);
      }
      if (c < 8) {
        const f32x4 sm4 = *(const f32x4*)&A.summT[(size_t)k * 512 + i0 + 4 * g];
        const f32x4 ix4 = *(const f32x4*)&A.invxT[(size_t)k * 512 + i0 + 4 * g];
        f32x4 p4;
        #pragma unroll
        for (int j = 0; j < 4; ++j)
          p4[j] = tanh_fast((acc[j] - sm4[j] * syb) * ix4[j] * iyb);
        *(f32x4*)&A.pP[(size_t)(b0 + c) * 8192 + (size_t)k * 512 + i0 + 4 * g] = p4;
      } else {
        *(f32x4*)&A.aB[R][(size_t)(b0 + c - 8) * 8192 + (size_t)k * 512 + i0 + 4 * g] = acc;
      }
    }
  }
}

// ===================== launch =====================
extern "C" void kernel_launch(void* const* d_in, const int* in_sizes, int n_in,
                              void* d_out, int out_size, void* d_ws, size_t ws_size,
                              hipStream_t stream) {
  char* w = (char*)d_ws;
  KArgs A;
  A.m  = (const float*)d_in[0];
  A.q  = (const float*)d_in[1];
  A.Ww = (const float*)d_in[2];
  A.Wb = (const float*)d_in[3];
  A.Hb     = (ushort*)(w + 0);          // 1048576
  A.HTb    = (ushort*)(w + 1048576);    // 1048576
  A.Yb0    = (ushort*)(w + 2097152);    // 262144
  A.Yb1    = (ushort*)(w + 2359296);    // 262144
  A.Vb0    = (ushort*)(w + 2621440);    // 262144
  A.pP     = (float*)(w + 2883584);     // 4194304
  A.aB[0]  = (float*)(w + 7077888);     // 4194304
  A.aB[1]  = (float*)(w + 11272192);    // 4194304
  A.summT  = (float*)(w + 15466496);    // 32768
  A.invxT  = (float*)(w + 15499264);    // 32768
  A.syT0   = (float*)(w + 15532032);    // 8192
  A.invyT0 = (float*)(w + 15540224);    // 8192
  A.outp = (float*)d_out;

  k_gemm<<<320, 256, 0, stream>>>(A);
  k_round<0><<<256, 256, 0, stream>>>(A);
  k_round<1><<<256, 256, 0, stream>>>(A);
  k_round<2><<<256, 256, 0, stream>>>(A);
}

// Round 15
// 79.478 us; speedup vs baseline: 2.5722x; 1.0606x over previous
//
#include <hip/hip_runtime.h>
#include <hip/hip_bf16.h>
#include <cstdint>
#include <cstddef>

#define IC 512     // in_caps
#define IDM 768    // in_dim
#define KC 16      // num_caps
#define NB 128     // batch
#define NOUT 1024  // KC*DC

typedef __attribute__((ext_vector_type(8))) short short8v;
typedef __attribute__((ext_vector_type(4))) float f32x4;

#define MFMA __builtin_amdgcn_mfma_f32_16x16x32_bf16

static __device__ __forceinline__ unsigned fbits(float x) {
  union { float f; unsigned u; } z; z.f = x; return z.u;
}
static __device__ __forceinline__ float bf_f(ushort u) {
  union { float f; unsigned u32; } z; z.u32 = ((unsigned)u) << 16; return z.f;
}
static __device__ __forceinline__ ushort bf_rne(float x) {
  __hip_bfloat16 h = __float2bfloat16(x);
  return *reinterpret_cast<ushort*>(&h);
}
// truncation hi/lo split (GEMM input path only)
static __device__ __forceinline__ void split2(float x, ushort& h, ushort& l) {
  h = (ushort)(fbits(x) >> 16);
  const float r = x - bf_f(h);
  l = (ushort)(fbits(r) >> 16);
}
static __device__ __forceinline__ void split8(const float* p, short8v& h, short8v& l) {
  const float4 x0 = *(const float4*)p;
  const float4 x1 = *(const float4*)(p + 4);
  const float xs[8] = {x0.x, x0.y, x0.z, x0.w, x1.x, x1.y, x1.z, x1.w};
  #pragma unroll
  for (int j = 0; j < 8; ++j) {
    ushort hh, ll; split2(xs[j], hh, ll);
    h[j] = (short)hh; l[j] = (short)ll;
  }
}

struct KArgs {
  const float *m, *q, *Ww, *Wb;
  ushort *Hb, *HTb;          // hat_m bf16 [i][n] and [n][i]
  ushort *Yb[3];             // y per round, bf16 chain
  ushort *Vb[2];             // vsum per round, bf16 chain
  ushort *Db[3];             // dsp per round [b][k*512+i], bf16
  float *summT, *invxT;      // hat_m row stats (of bf16 values), [k][i]
  float *syT[3], *invyT[3];  // y row stats (of bf16 values), [k][b]
  float *outp;
};

// ===================== K1: GEMM (hi/lo f32-accurate) + bf16 epilogue ============
// Verbatim R9-verified kernel (2D XCD partition).
__global__ __launch_bounds__(256) void k_gemm(KArgs A)
{
  __shared__ float sred[2][2][32];
  const int t = threadIdx.x;
  const int bid = blockIdx.x;
  const int region = bid & 7, idx = bid >> 3;
  const int rt = (region & 1) * 10 + (idx % 10);
  const int nt = (region >> 1) * 4 + (idx / 10);
  const int w = t >> 6, L = t & 63, c = L & 15, g = L >> 4;
  const int wr = w >> 1, wc = w & 1;
  const int r0 = rt * 32, n0 = nt * 64;
  const int arow = r0 + wr * 16 + c;
  const int bcol = n0 + wc * 32 + c;
  const float* asrc = (arow < IC) ? (A.m + (size_t)arow * IDM)
                                  : (A.q + (size_t)(arow - IC) * IDM);
  const float* b0src = A.Ww + (size_t)bcol * IDM;
  const float* b1src = A.Ww + (size_t)(bcol + 16) * IDM;

  f32x4 acc0 = {}, acc1 = {};
  #pragma unroll 2
  for (int kb = 0; kb < IDM; kb += 32) {
    short8v ah, al, bh0, bl0, bh1, bl1;
    split8(asrc + kb + g * 8, ah, al);
    split8(b0src + kb + g * 8, bh0, bl0);
    split8(b1src + kb + g * 8, bh1, bl1);
    acc0 = MFMA(ah, bh0, acc0, 0, 0, 0);
    acc0 = MFMA(ah, bl0, acc0, 0, 0, 0);
    acc0 = MFMA(al, bh0, acc0, 0, 0, 0);
    acc1 = MFMA(ah, bh1, acc1, 0, 0, 0);
    acc1 = MFMA(ah, bl1, acc1, 0, 0, 0);
    acc1 = MFMA(al, bh1, acc1, 0, 0, 0);
  }

  const float bias0 = A.Wb[bcol];
  const float bias1 = A.Wb[bcol + 16];
  ushort h0[4], h1[4];
  float r0s[4], r1s[4];
  #pragma unroll
  for (int j = 0; j < 4; ++j) {
    h0[j] = bf_rne(acc0[j] + bias0); r0s[j] = bf_f(h0[j]);
    h1[j] = bf_rne(acc1[j] + bias1); r1s[j] = bf_f(h1[j]);
  }

  #pragma unroll
  for (int j = 0; j < 4; ++j) {
    float s = r0s[j] + r1s[j];
    float q2 = r0s[j] * r0s[j] + r1s[j] * r1s[j];
    #pragma unroll
    for (int off = 1; off < 16; off <<= 1) {
      s += __shfl_xor(s, off);
      q2 += __shfl_xor(q2, off);
    }
    if (c == 0) {
      sred[wc][0][wr * 16 + 4 * g + j] = s;
      sred[wc][1][wr * 16 + 4 * g + j] = q2;
    }
  }

  const int rowb = r0 + wr * 16 + 4 * g;
  if (rowb < IC) {
    #pragma unroll
    for (int j = 0; j < 4; ++j) {
      const size_t r = (size_t)(rowb + j) * NOUT;
      A.Hb[r + bcol] = h0[j];
      A.Hb[r + bcol + 16] = h1[j];
    }
    *(ushort4*)&A.HTb[(size_t)bcol * 512 + rowb] = make_ushort4(h0[0], h0[1], h0[2], h0[3]);
    *(ushort4*)&A.HTb[(size_t)(bcol + 16) * 512 + rowb] = make_ushort4(h1[0], h1[1], h1[2], h1[3]);
  } else {
    #pragma unroll
    for (int j = 0; j < 4; ++j) {
      const size_t r = (size_t)(rowb + j - IC) * NOUT;
      A.Yb[0][r + bcol] = h0[j];
      A.Yb[0][r + bcol + 16] = h1[j];
    }
  }
  __syncthreads();
  if (t < 32) {
    const int row = r0 + t;
    const float s = sred[0][0][t] + sred[1][0][t];
    const float q2 = sred[0][1][t] + sred[1][1][t];
    const float inv = rsqrtf(q2 - s * s * (1.0f / 64.0f));
    if (row < IC) {
      A.summT[nt * 512 + row] = s;
      A.invxT[nt * 512 + row] = inv;
    } else {
      A.syT[0][nt * 128 + (row - IC)] = s;
      A.invyT[0][nt * 128 + (row - IC)] = inv;
    }
  }
}

// ===================== K2: corr + softmax (1024 thr, wave = one k) ==============
// Verbatim R9-verified kernel (XCD b-ownership: bt = bid&7).
template <int RR>   // 0: round 0 (uniform d, no a-dot); 1: rounds 1,2
__global__ __launch_bounds__(1024) void k_corr(KArgs A)
{
  __shared__ float p_lds[16][256];
  __shared__ float a_lds[16][256];
  const int t = threadIdx.x;
  const int bid = blockIdx.x;
  const int bt = bid & 7, it = bid >> 3;
  const int i0 = it * 16, b0 = bt * 16;
  const int k = t >> 6, L = t & 63, c = L & 15, g = L >> 4;

  const ushort* Yb = A.Yb[RR == 0 ? 0 : (RR == 1 ? 1 : 2)];
  const ushort* Vb = A.Vb[RR == 2 ? 1 : 0];
  const float* syT = A.syT[RR == 0 ? 0 : (RR == 1 ? 1 : 2)];
  const float* invyT = A.invyT[RR == 0 ? 0 : (RR == 1 ? 1 : 2)];
  ushort* Db = A.Db[RR == 0 ? 0 : (RR == 1 ? 1 : 2)];

  const size_t koff = (size_t)k * 64 + g * 8;
  const ushort* pH = A.Hb + (size_t)(i0 + c) * NOUT + koff;
  const ushort* pY = Yb + (size_t)(b0 + c) * NOUT + koff;
  const ushort* pV = Vb + (size_t)(b0 + c) * NOUT + koff;

  f32x4 P = {}, Aa = {};
  #pragma unroll
  for (int ks = 0; ks < 64; ks += 32) {
    const short8v ah = *(const short8v*)(pH + ks);
    const short8v yh = *(const short8v*)(pY + ks);
    P = MFMA(ah, yh, P, 0, 0, 0);
    if (RR) {
      const short8v vh = *(const short8v*)(pV + ks);
      Aa = MFMA(ah, vh, Aa, 0, 0, 0);
    }
  }

  const float syb = syT[k * 128 + b0 + c];
  const float iyb = invyT[k * 128 + b0 + c];
  const f32x4 sm4 = *(const f32x4*)&A.summT[k * 512 + i0 + 4 * g];
  const f32x4 ix4 = *(const f32x4*)&A.invxT[k * 512 + i0 + 4 * g];
  f32x4 pv;
  #pragma unroll
  for (int j = 0; j < 4; ++j)
    pv[j] = tanhf((P[j] - sm4[j] * syb * (1.0f / 64.0f)) * ix4[j] * iyb);
  *(f32x4*)&p_lds[k][c * 16 + 4 * g] = pv;
  if (RR) *(f32x4*)&a_lds[k][c * 16 + 4 * g] = Aa;
  __syncthreads();

  if (t < 256) {
    const int bl = t >> 4, il = t & 15;
    const size_t dbase = (size_t)(b0 + bl) * 8192 + (size_t)(i0 + il);
    if (RR == 0) {
      #pragma unroll
      for (int kk = 0; kk < 16; ++kk)
        Db[dbase + (size_t)kk * 512] = bf_rne(0.0625f - p_lds[kk][t]);
    } else {
      float av[16];
      float mx = -1e30f;
      #pragma unroll
      for (int kk = 0; kk < 16; ++kk) { av[kk] = a_lds[kk][t]; mx = fmaxf(mx, av[kk]); }
      float s = 0.f;
      #pragma unroll
      for (int kk = 0; kk < 16; ++kk) { av[kk] = __expf(av[kk] - mx); s += av[kk]; }
      const float inv = 1.0f / s;
      #pragma unroll
      for (int kk = 0; kk < 16; ++kk)
        Db[dbase + (size_t)kk * 512] = bf_rne(av[kk] * inv - p_lds[kk][t]);
    }
  }
}

// ===================== K3: hat_v MFMA + squash + y/vsum update ==================
// CHANGED vs R9: 256 blocks (k = bid>>4, bt = bid&15), 8 b's per block.
// A-operand rows 8-15 zero-padded (R14-verified pattern); outputs g<2; stats t<8.
template <int R>   // 0: vsum=v; 1: vsum+=v; 2: final (outp only)
__global__ __launch_bounds__(256) void k_hatv(KArgs A)
{
  __shared__ float red[3][4][16];
  __shared__ float sscale[16];
  const int t = threadIdx.x;
  const int bid = blockIdx.x;
  const int w = t >> 6, L = t & 63, c = L & 15, g = L >> 4;
  const int k = bid >> 4;
  const int b0 = (bid & 15) * 8;
  const int cb = c & 7;
  const short8v zfrag = {};

  const ushort* Db = A.Db[R];
  const ushort* Ybin = (R == 2) ? nullptr : A.Yb[R];
  ushort* Ybout = (R == 2) ? nullptr : A.Yb[R + 1];
  const ushort* Vbin = (R == 1) ? A.Vb[0] : nullptr;
  ushort* Vbout = (R == 2) ? nullptr : A.Vb[R];
  float* syout = (R == 2) ? nullptr : A.syT[R + 1];
  float* invyout = (R == 2) ? nullptr : A.invyT[R + 1];

  const ushort* pA = Db + (size_t)(b0 + cb) * 8192 + (size_t)k * 512 + g * 8;
  const ushort* pB = A.HTb + (size_t)(k * 64 + w * 16 + c) * 512 + g * 8;

  f32x4 acc = {};
  #pragma unroll 8
  for (int i = 0; i < 512; i += 32) {
    const short8v ld = *(const short8v*)(pA + i);
    const short8v ab = (c < 8) ? ld : zfrag;
    const short8v bb = *(const short8v*)(pB + i);
    acc = MFMA(ab, bb, acc, 0, 0, 0);
  }

  float sq[4];
  #pragma unroll
  for (int j = 0; j < 4; ++j) {
    sq[j] = acc[j] * acc[j];
    #pragma unroll
    for (int off = 1; off < 16; off <<= 1) sq[j] += __shfl_xor(sq[j], off);
  }
  if (c == 0) {
    #pragma unroll
    for (int j = 0; j < 4; ++j) red[0][w][4 * g + j] = sq[j];
  }
  __syncthreads();
  if (t < 16) {
    const float s = red[0][0][t] + red[0][1][t] + red[0][2][t] + red[0][3][t];
    sscale[t] = (s / (1.0f + s)) * rsqrtf(s + 1e-8f);
  }
  __syncthreads();

  const int d = w * 16 + c;
  if (R == 2) {
    if (g < 2) {
      #pragma unroll
      for (int j = 0; j < 4; ++j)
        A.outp[(size_t)(b0 + 4 * g + j) * 1024 + (size_t)k * 64 + d] =
            acc[j] * sscale[4 * g + j];
    }
  } else {
    float s1[4] = {0.f, 0.f, 0.f, 0.f}, s2[4] = {0.f, 0.f, 0.f, 0.f};
    if (g < 2) {
      #pragma unroll
      for (int j = 0; j < 4; ++j) {
        const int b = 4 * g + j;
        const size_t gi = (size_t)(b0 + b) * 1024 + (size_t)k * 64 + d;
        const float v = acc[j] * sscale[b];
        const float vs = (R == 0) ? v : (bf_f(Vbin[gi]) + v);
        Vbout[gi] = bf_rne(vs);
        const float yn = (bf_f(Ybin[gi]) + v) * 0.5f;
        const ushort ynb = bf_rne(yn);
        Ybout[gi] = ynb;
        const float ynr = bf_f(ynb);   // stats of the bf16 y that corr will dot
        s1[j] = ynr; s2[j] = ynr * ynr;
      }
    }
    #pragma unroll
    for (int j = 0; j < 4; ++j) {
      #pragma unroll
      for (int off = 1; off < 16; off <<= 1) {
        s1[j] += __shfl_xor(s1[j], off);
        s2[j] += __shfl_xor(s2[j], off);
      }
    }
    if (c == 0) {
      #pragma unroll
      for (int j = 0; j < 4; ++j) {
        red[1][w][4 * g + j] = s1[j];
        red[2][w][4 * g + j] = s2[j];
      }
    }
    __syncthreads();
    if (t < 8) {
      const float s = red[1][0][t] + red[1][1][t] + red[1][2][t] + red[1][3][t];
      const float q2 = red[2][0][t] + red[2][1][t] + red[2][2][t] + red[2][3][t];
      syout[k * 128 + b0 + t] = s;
      invyout[k * 128 + b0 + t] = rsqrtf(q2 - s * s * (1.0f / 64.0f));
    }
  }
}

// ===================== launch =====================
extern "C" void kernel_launch(void* const* d_in, const int* in_sizes, int n_in,
                              void* d_out, int out_size, void* d_ws, size_t ws_size,
                              hipStream_t stream) {
  char* w = (char*)d_ws;
  KArgs A;
  A.m  = (const float*)d_in[0];
  A.q  = (const float*)d_in[1];
  A.Ww = (const float*)d_in[2];
  A.Wb = (const float*)d_in[3];
  A.Hb   = (ushort*)(w + 0);          // 1048576
  A.HTb  = (ushort*)(w + 1048576);    // 1048576
  A.Yb[0] = (ushort*)(w + 2097152);   // 262144 each
  A.Yb[1] = (ushort*)(w + 2359296);
  A.Yb[2] = (ushort*)(w + 2621440);
  A.Vb[0] = (ushort*)(w + 2883584);   // 262144 each
  A.Vb[1] = (ushort*)(w + 3145728);
  A.Db[0] = (ushort*)(w + 3407872);   // 2097152 each
  A.Db[1] = (ushort*)(w + 5505024);
  A.Db[2] = (ushort*)(w + 7602176);
  A.summT = (float*)(w + 9699328);    // 32768
  A.invxT = (float*)(w + 9732096);    // 32768
  A.syT[0]   = (float*)(w + 9764864);   // 8192 each
  A.syT[1]   = (float*)(w + 9773056);
  A.syT[2]   = (float*)(w + 9781248);
  A.invyT[0] = (float*)(w + 9789440);
  A.invyT[1] = (float*)(w + 9797632);
  A.invyT[2] = (float*)(w + 9805824);
  A.outp = (float*)d_out;

  k_gemm<<<320, 256, 0, stream>>>(A);
  k_corr<0><<<256, 1024, 0, stream>>>(A);
  k_hatv<0><<<256, 256, 0, stream>>>(A);
  k_corr<1><<<256, 1024, 0, stream>>>(A);
  k_hatv<1><<<256, 256, 0, stream>>>(A);
  k_corr<2><<<256, 1024, 0, stream>>>(A);
  k_hatv<2><<<256, 256, 0, stream>>>(A);
}

// Round 16
// 76.811 us; speedup vs baseline: 2.6615x; 1.0347x over previous
//
#include <hip/hip_runtime.h>
#include <hip/hip_bf16.h>
#include <cstdint>
#include <cstddef>

#define IC 512     // in_caps
#define IDM 768    // in_dim
#define KC 16      // num_caps
#define NB 128     // batch
#define NOUT 1024  // KC*DC

typedef __attribute__((ext_vector_type(8))) short short8v;
typedef __attribute__((ext_vector_type(4))) float f32x4;

#define MFMA __builtin_amdgcn_mfma_f32_16x16x32_bf16

static __device__ __forceinline__ unsigned fbits(float x) {
  union { float f; unsigned u; } z; z.f = x; return z.u;
}
static __device__ __forceinline__ float bf_f(ushort u) {
  union { float f; unsigned u32; } z; z.u32 = ((unsigned)u) << 16; return z.f;
}
static __device__ __forceinline__ ushort bf_rne(float x) {
  __hip_bfloat16 h = __float2bfloat16(x);
  return *reinterpret_cast<ushort*>(&h);
}
// truncation hi/lo split (GEMM input path only)
static __device__ __forceinline__ void split2(float x, ushort& h, ushort& l) {
  h = (ushort)(fbits(x) >> 16);
  const float r = x - bf_f(h);
  l = (ushort)(fbits(r) >> 16);
}
static __device__ __forceinline__ void split8(const float* p, short8v& h, short8v& l) {
  const float4 x0 = *(const float4*)p;
  const float4 x1 = *(const float4*)(p + 4);
  const float xs[8] = {x0.x, x0.y, x0.z, x0.w, x1.x, x1.y, x1.z, x1.w};
  #pragma unroll
  for (int j = 0; j < 8; ++j) {
    ushort hh, ll; split2(xs[j], hh, ll);
    h[j] = (short)hh; l[j] = (short)ll;
  }
}

struct KArgs {
  const float *m, *q, *Ww, *Wb;
  ushort *Hb, *HTb;          // hat_m bf16 [i][n] and [n][i]
  ushort *Yb[3];             // y per round, bf16 chain
  ushort *Vb[2];             // vsum per round, bf16 chain
  ushort *Db[3];             // dsp per round [b][k*512+i], bf16
  float *summT, *invxT;      // hat_m row stats (of bf16 values), [k][i]
  float *syT[3], *invyT[3];  // y row stats (of bf16 values), [k][b]
  float *outp;
};

// ===================== K1: GEMM (hi/lo f32-accurate) + bf16 epilogue ============
// 2D XCD partition: region = bid%8 owns a 10(rt) x 4(nt) tile patch.
__global__ __launch_bounds__(256) void k_gemm(KArgs A)
{
  __shared__ float sred[2][2][32];
  const int t = threadIdx.x;
  const int bid = blockIdx.x;
  const int region = bid & 7, idx = bid >> 3;
  const int rt = (region & 1) * 10 + (idx % 10);
  const int nt = (region >> 1) * 4 + (idx / 10);
  const int w = t >> 6, L = t & 63, c = L & 15, g = L >> 4;
  const int wr = w >> 1, wc = w & 1;
  const int r0 = rt * 32, n0 = nt * 64;
  const int arow = r0 + wr * 16 + c;
  const int bcol = n0 + wc * 32 + c;
  const float* asrc = (arow < IC) ? (A.m + (size_t)arow * IDM)
                                  : (A.q + (size_t)(arow - IC) * IDM);
  const float* b0src = A.Ww + (size_t)bcol * IDM;
  const float* b1src = A.Ww + (size_t)(bcol + 16) * IDM;

  f32x4 acc0 = {}, acc1 = {};
  #pragma unroll 2
  for (int kb = 0; kb < IDM; kb += 32) {
    short8v ah, al, bh0, bl0, bh1, bl1;
    split8(asrc + kb + g * 8, ah, al);
    split8(b0src + kb + g * 8, bh0, bl0);
    split8(b1src + kb + g * 8, bh1, bl1);
    acc0 = MFMA(ah, bh0, acc0, 0, 0, 0);
    acc0 = MFMA(ah, bl0, acc0, 0, 0, 0);
    acc0 = MFMA(al, bh0, acc0, 0, 0, 0);
    acc1 = MFMA(ah, bh1, acc1, 0, 0, 0);
    acc1 = MFMA(ah, bl1, acc1, 0, 0, 0);
    acc1 = MFMA(al, bh1, acc1, 0, 0, 0);
  }

  const float bias0 = A.Wb[bcol];
  const float bias1 = A.Wb[bcol + 16];
  ushort h0[4], h1[4];
  float r0s[4], r1s[4];
  #pragma unroll
  for (int j = 0; j < 4; ++j) {
    h0[j] = bf_rne(acc0[j] + bias0); r0s[j] = bf_f(h0[j]);
    h1[j] = bf_rne(acc1[j] + bias1); r1s[j] = bf_f(h1[j]);
  }

  #pragma unroll
  for (int j = 0; j < 4; ++j) {
    float s = r0s[j] + r1s[j];
    float q2 = r0s[j] * r0s[j] + r1s[j] * r1s[j];
    #pragma unroll
    for (int off = 1; off < 16; off <<= 1) {
      s += __shfl_xor(s, off);
      q2 += __shfl_xor(q2, off);
    }
    if (c == 0) {
      sred[wc][0][wr * 16 + 4 * g + j] = s;
      sred[wc][1][wr * 16 + 4 * g + j] = q2;
    }
  }

  const int rowb = r0 + wr * 16 + 4 * g;
  if (rowb < IC) {
    #pragma unroll
    for (int j = 0; j < 4; ++j) {
      const size_t r = (size_t)(rowb + j) * NOUT;
      A.Hb[r + bcol] = h0[j];
      A.Hb[r + bcol + 16] = h1[j];
    }
    *(ushort4*)&A.HTb[(size_t)bcol * 512 + rowb] = make_ushort4(h0[0], h0[1], h0[2], h0[3]);
    *(ushort4*)&A.HTb[(size_t)(bcol + 16) * 512 + rowb] = make_ushort4(h1[0], h1[1], h1[2], h1[3]);
  } else {
    #pragma unroll
    for (int j = 0; j < 4; ++j) {
      const size_t r = (size_t)(rowb + j - IC) * NOUT;
      A.Yb[0][r + bcol] = h0[j];
      A.Yb[0][r + bcol + 16] = h1[j];
    }
  }
  __syncthreads();
  if (t < 32) {
    const int row = r0 + t;
    const float s = sred[0][0][t] + sred[1][0][t];
    const float q2 = sred[0][1][t] + sred[1][1][t];
    const float inv = rsqrtf(q2 - s * s * (1.0f / 64.0f));
    if (row < IC) {
      A.summT[nt * 512 + row] = s;
      A.invxT[nt * 512 + row] = inv;
    } else {
      A.syT[0][nt * 128 + (row - IC)] = s;
      A.invyT[0][nt * 128 + (row - IC)] = inv;
    }
  }
}

// ===================== K2: corr + softmax (1024 thr, wave = one k) ==============
// Block: (i-tile 16, b-tile 16); grid 256. XCD b-ownership: bt = bid&7.
template <int RR>   // 0: round 0 (uniform d, no a-dot); 1: rounds 1,2
__global__ __launch_bounds__(1024) void k_corr(KArgs A)
{
  __shared__ float p_lds[16][256];
  __shared__ float a_lds[16][256];
  const int t = threadIdx.x;
  const int bid = blockIdx.x;
  const int bt = bid & 7, it = bid >> 3;
  const int i0 = it * 16, b0 = bt * 16;
  const int k = t >> 6, L = t & 63, c = L & 15, g = L >> 4;

  const ushort* Yb = A.Yb[RR == 0 ? 0 : (RR == 1 ? 1 : 2)];
  const ushort* Vb = A.Vb[RR == 2 ? 1 : 0];
  const float* syT = A.syT[RR == 0 ? 0 : (RR == 1 ? 1 : 2)];
  const float* invyT = A.invyT[RR == 0 ? 0 : (RR == 1 ? 1 : 2)];
  ushort* Db = A.Db[RR == 0 ? 0 : (RR == 1 ? 1 : 2)];

  const size_t koff = (size_t)k * 64 + g * 8;
  const ushort* pH = A.Hb + (size_t)(i0 + c) * NOUT + koff;
  const ushort* pY = Yb + (size_t)(b0 + c) * NOUT + koff;
  const ushort* pV = Vb + (size_t)(b0 + c) * NOUT + koff;

  f32x4 P = {}, Aa = {};
  #pragma unroll
  for (int ks = 0; ks < 64; ks += 32) {
    const short8v ah = *(const short8v*)(pH + ks);
    const short8v yh = *(const short8v*)(pY + ks);
    P = MFMA(ah, yh, P, 0, 0, 0);
    if (RR) {
      const short8v vh = *(const short8v*)(pV + ks);
      Aa = MFMA(ah, vh, Aa, 0, 0, 0);
    }
  }

  const float syb = syT[k * 128 + b0 + c];
  const float iyb = invyT[k * 128 + b0 + c];
  const f32x4 sm4 = *(const f32x4*)&A.summT[k * 512 + i0 + 4 * g];
  const f32x4 ix4 = *(const f32x4*)&A.invxT[k * 512 + i0 + 4 * g];
  f32x4 pv;
  #pragma unroll
  for (int j = 0; j < 4; ++j)
    pv[j] = tanhf((P[j] - sm4[j] * syb * (1.0f / 64.0f)) * ix4[j] * iyb);
  *(f32x4*)&p_lds[k][c * 16 + 4 * g] = pv;
  if (RR) *(f32x4*)&a_lds[k][c * 16 + 4 * g] = Aa;
  __syncthreads();

  if (t < 256) {
    const int bl = t >> 4, il = t & 15;
    const size_t dbase = (size_t)(b0 + bl) * 8192 + (size_t)(i0 + il);
    if (RR == 0) {
      #pragma unroll
      for (int kk = 0; kk < 16; ++kk)
        Db[dbase + (size_t)kk * 512] = bf_rne(0.0625f - p_lds[kk][t]);
    } else {
      float av[16];
      float mx = -1e30f;
      #pragma unroll
      for (int kk = 0; kk < 16; ++kk) { av[kk] = a_lds[kk][t]; mx = fmaxf(mx, av[kk]); }
      float s = 0.f;
      #pragma unroll
      for (int kk = 0; kk < 16; ++kk) { av[kk] = __expf(av[kk] - mx); s += av[kk]; }
      const float inv = 1.0f / s;
      #pragma unroll
      for (int kk = 0; kk < 16; ++kk)
        Db[dbase + (size_t)kk * 512] = bf_rne(av[kk] * inv - p_lds[kk][t]);
    }
  }
}

// ===================== K3: hat_v MFMA + squash + y/vsum update ==================
// Block: (k, 16 b); grid 128. XCD b-ownership: btile = bid&7.
template <int R>   // 0: vsum=v; 1: vsum+=v; 2: final (outp only)
__global__ __launch_bounds__(256) void k_hatv(KArgs A)
{
  __shared__ float red[3][4][16];
  __shared__ float sscale[16];
  const int t = threadIdx.x;
  const int bid = blockIdx.x;
  const int w = t >> 6, L = t & 63, c = L & 15, g = L >> 4;
  const int k = bid >> 3;
  const int b0 = (bid & 7) * 16;

  const ushort* Db = A.Db[R];
  const ushort* Ybin = (R == 2) ? nullptr : A.Yb[R];
  ushort* Ybout = (R == 2) ? nullptr : A.Yb[R + 1];
  const ushort* Vbin = (R == 1) ? A.Vb[0] : nullptr;
  ushort* Vbout = (R == 2) ? nullptr : A.Vb[R];
  float* syout = (R == 2) ? nullptr : A.syT[R + 1];
  float* invyout = (R == 2) ? nullptr : A.invyT[R + 1];

  const ushort* pA = Db + (size_t)(b0 + c) * 8192 + (size_t)k * 512 + g * 8;
  const ushort* pB = A.HTb + (size_t)(k * 64 + w * 16 + c) * 512 + g * 8;

  f32x4 acc = {};
  #pragma unroll 8
  for (int i = 0; i < 512; i += 32) {
    const short8v ab = *(const short8v*)(pA + i);
    const short8v bb = *(const short8v*)(pB + i);
    acc = MFMA(ab, bb, acc, 0, 0, 0);
  }

  float sq[4];
  #pragma unroll
  for (int j = 0; j < 4; ++j) {
    sq[j] = acc[j] * acc[j];
    #pragma unroll
    for (int off = 1; off < 16; off <<= 1) sq[j] += __shfl_xor(sq[j], off);
  }
  if (c == 0) {
    #pragma unroll
    for (int j = 0; j < 4; ++j) red[0][w][4 * g + j] = sq[j];
  }
  __syncthreads();
  if (t < 16) {
    const float s = red[0][0][t] + red[0][1][t] + red[0][2][t] + red[0][3][t];
    sscale[t] = (s / (1.0f + s)) * rsqrtf(s + 1e-8f);
  }
  __syncthreads();

  const int d = w * 16 + c;
  float s1[4], s2[4];
  #pragma unroll
  for (int j = 0; j < 4; ++j) {
    const int bl_ = 4 * g + j;
    const int b = b0 + bl_;
    const float v = acc[j] * sscale[bl_];
    const size_t idx = (size_t)b * NOUT + (size_t)k * 64 + d;
    if (R == 2) {
      A.outp[idx] = v;
    } else {
      const float vs = (R == 0) ? v : (bf_f(Vbin[idx]) + v);
      Vbout[idx] = bf_rne(vs);
      const float yn = (bf_f(Ybin[idx]) + v) * 0.5f;
      const ushort ynb = bf_rne(yn);
      Ybout[idx] = ynb;
      const float ynr = bf_f(ynb);   // stats of the bf16 y that corr will dot
      s1[j] = ynr; s2[j] = ynr * ynr;
    }
  }
  if (R != 2) {
    #pragma unroll
    for (int j = 0; j < 4; ++j) {
      #pragma unroll
      for (int off = 1; off < 16; off <<= 1) {
        s1[j] += __shfl_xor(s1[j], off);
        s2[j] += __shfl_xor(s2[j], off);
      }
    }
    if (c == 0) {
      #pragma unroll
      for (int j = 0; j < 4; ++j) {
        red[1][w][4 * g + j] = s1[j];
        red[2][w][4 * g + j] = s2[j];
      }
    }
    __syncthreads();
    if (t < 16) {
      const float s = red[1][0][t] + red[1][1][t] + red[1][2][t] + red[1][3][t];
      const float q2 = red[2][0][t] + red[2][1][t] + red[2][2][t] + red[2][3][t];
      syout[k * 128 + b0 + t] = s;
      invyout[k * 128 + b0 + t] = rsqrtf(q2 - s * s * (1.0f / 64.0f));
    }
  }
}

// ===================== launch =====================
extern "C" void kernel_launch(void* const* d_in, const int* in_sizes, int n_in,
                              void* d_out, int out_size, void* d_ws, size_t ws_size,
                              hipStream_t stream) {
  char* w = (char*)d_ws;
  KArgs A;
  A.m  = (const float*)d_in[0];
  A.q  = (const float*)d_in[1];
  A.Ww = (const float*)d_in[2];
  A.Wb = (const float*)d_in[3];
  A.Hb   = (ushort*)(w + 0);          // 1048576
  A.HTb  = (ushort*)(w + 1048576);    // 1048576
  A.Yb[0] = (ushort*)(w + 2097152);   // 262144 each
  A.Yb[1] = (ushort*)(w + 2359296);
  A.Yb[2] = (ushort*)(w + 2621440);
  A.Vb[0] = (ushort*)(w + 2883584);   // 262144 each
  A.Vb[1] = (ushort*)(w + 3145728);
  A.Db[0] = (ushort*)(w + 3407872);   // 2097152 each
  A.Db[1] = (ushort*)(w + 5505024);
  A.Db[2] = (ushort*)(w + 7602176);
  A.summT = (float*)(w + 9699328);    // 32768
  A.invxT = (float*)(w + 9732096);    // 32768
  A.syT[0]   = (float*)(w + 9764864);   // 8192 each
  A.syT[1]   = (float*)(w + 9773056);
  A.syT[2]   = (float*)(w + 9781248);
  A.invyT[0] = (float*)(w + 9789440);
  A.invyT[1] = (float*)(w + 9797632);
  A.invyT[2] = (float*)(w + 9805824);
  A.outp = (float*)d_out;

  k_gemm<<<320, 256, 0, stream>>>(A);
  k_corr<0><<<256, 1024, 0, stream>>>(A);
  k_hatv<0><<<128, 256, 0, stream>>>(A);
  k_corr<1><<<256, 1024, 0, stream>>>(A);
  k_hatv<1><<<128, 256, 0, stream>>>(A);
  k_corr<2><<<256, 1024, 0, stream>>>(A);
  k_hatv<2><<<128, 256, 0, stream>>>(A);
}